// Round 12
// baseline (6002.922 us; speedup 1.0000x reference)
//
#include <hip/hip_runtime.h>
#include <math.h>

#define BB 64
#define TT 512
#define II 64
#define HH 512
#define NBLK 192
#define FLAG_STRIDE 32   // dwords = 128 B between flags

typedef __attribute__((ext_vector_type(8))) short bf16x8;
typedef __attribute__((ext_vector_type(16))) float f32x16;

__device__ __forceinline__ float sigmoidf_(float x) {
    return 1.0f / (1.0f + expf(-x));
}
__device__ __forceinline__ unsigned short f2bf(float f) {
    union { float f; unsigned u; } v; v.f = f;
    unsigned r = v.u + 0x7fffu + ((v.u >> 16) & 1u);   // RTNE
    return (unsigned short)(r >> 16);
}
__device__ __forceinline__ float bf2f(unsigned short s) {
    union { unsigned u; float f; } v; v.u = ((unsigned)s) << 16;
    return v.f;
}

// --- coherent scalar primitives (compiler-tracked) ---
__device__ __forceinline__ void store8_thru(void* p, unsigned long long u) {
    __hip_atomic_store((unsigned long long*)p, u, __ATOMIC_RELAXED, __HIP_MEMORY_SCOPE_AGENT);
}
__device__ __forceinline__ void storef_thru(float* p, float v) {
    __hip_atomic_store(p, v, __ATOMIC_RELAXED, __HIP_MEMORY_SCOPE_AGENT);
}
__device__ __forceinline__ float loadf_byp(const float* p) {
    return __hip_atomic_load(p, __ATOMIC_RELAXED, __HIP_MEMORY_SCOPE_AGENT);
}
__device__ __forceinline__ void storeu_thru(unsigned* p, unsigned v) {
    __hip_atomic_store(p, v, __ATOMIC_RELAXED, __HIP_MEMORY_SCOPE_AGENT);
}
__device__ __forceinline__ unsigned loadu_byp(const unsigned* p) {
    return __hip_atomic_load(p, __ATOMIC_RELAXED, __HIP_MEMORY_SCOPE_AGENT);
}

// Wave-parallel direct poll: lane i watches producer i's spread flag line (bypass).
__device__ __forceinline__ void poll_ge64(const unsigned* flags, unsigned tgt) {
    const int lane = threadIdx.x & 63;
    const unsigned* a = flags + (size_t)lane * FLAG_STRIDE;
    unsigned f = loadu_byp(a);
    while (__ballot(f < tgt) != 0ull) {
        __builtin_amdgcn_s_sleep(1);
        f = loadu_byp(a);
    }
}

// L1+L2 invalidate (agent-scope acquire pattern). Per-wave, ordered before
// this wave's subsequent vmem by HW pipeline order (same as LLVM fence codegen).
__device__ __forceinline__ void l2_inv() {
    asm volatile("buffer_inv sc1" ::: "memory");
    __builtin_amdgcn_sched_barrier(0);
}

// --- 16B CACHED batched loads (8 ksteps = 16 dwordx4, stride 4096B) ---
// Coherence provided by l2_inv() after the step's flag-poll; producers write
// through (sc0 sc1 stores), so L2 never holds dirty lines for these buffers.
struct B8 { bf16x8 h0,h1,h2,h3,h4,h5,h6,h7, l0,l1,l2,l3,l4,l5,l6,l7; };

__device__ __forceinline__ void issue8(const char* rb, B8& b) {
    const char* p0 = rb;
    const char* p1 = rb + 4096;
    const char* p2 = rb + 8192;
    const char* p3 = rb + 12288;
    const char* p4 = rb + 16384;
    const char* p5 = rb + 20480;
    const char* p6 = rb + 24576;
    const char* p7 = rb + 28672;
    asm volatile(
        "global_load_dwordx4 %0, %16, off\n\t"
        "global_load_dwordx4 %8, %16, off offset:16\n\t"
        "global_load_dwordx4 %1, %17, off\n\t"
        "global_load_dwordx4 %9, %17, off offset:16\n\t"
        "global_load_dwordx4 %2, %18, off\n\t"
        "global_load_dwordx4 %10, %18, off offset:16\n\t"
        "global_load_dwordx4 %3, %19, off\n\t"
        "global_load_dwordx4 %11, %19, off offset:16\n\t"
        "global_load_dwordx4 %4, %20, off\n\t"
        "global_load_dwordx4 %12, %20, off offset:16\n\t"
        "global_load_dwordx4 %5, %21, off\n\t"
        "global_load_dwordx4 %13, %21, off offset:16\n\t"
        "global_load_dwordx4 %6, %22, off\n\t"
        "global_load_dwordx4 %14, %22, off offset:16\n\t"
        "global_load_dwordx4 %7, %23, off\n\t"
        "global_load_dwordx4 %15, %23, off offset:16"
        : "=&v"(b.h0), "=&v"(b.h1), "=&v"(b.h2), "=&v"(b.h3),
          "=&v"(b.h4), "=&v"(b.h5), "=&v"(b.h6), "=&v"(b.h7),
          "=&v"(b.l0), "=&v"(b.l1), "=&v"(b.l2), "=&v"(b.l3),
          "=&v"(b.l4), "=&v"(b.l5), "=&v"(b.l6), "=&v"(b.l7)
        : "v"(p0), "v"(p1), "v"(p2), "v"(p3), "v"(p4), "v"(p5), "v"(p6), "v"(p7));
}

// Counted waits; staged values tied through the asm (+sched_barrier, rule #18).
#define DEF_WAIT(NAME, CNT) \
__device__ __forceinline__ void NAME(B8& b) { \
    asm volatile("s_waitcnt vmcnt(" #CNT ")" \
        : "+v"(b.h0), "+v"(b.h1), "+v"(b.h2), "+v"(b.h3), \
          "+v"(b.h4), "+v"(b.h5), "+v"(b.h6), "+v"(b.h7), \
          "+v"(b.l0), "+v"(b.l1), "+v"(b.l2), "+v"(b.l3), \
          "+v"(b.l4), "+v"(b.l5), "+v"(b.l6), "+v"(b.l7)); \
    __builtin_amdgcn_sched_barrier(0); \
}
DEF_WAIT(wait32, 32)
DEF_WAIT(wait16, 16)
DEF_WAIT(wait0, 0)

#define MFMA_BF16 __builtin_amdgcn_mfma_f32_32x32x16_bf16

template<int S0>
__device__ __forceinline__ void consume8(const char* wa_h, const char* wa_l, const B8& b,
                                         f32x16& c0, f32x16& c1, f32x16& c2) {
#define KSTEP(J, BH, BL) { \
    bf16x8 ahi = *(const bf16x8*)(wa_h + (size_t)(S0 + J) * 2048); \
    bf16x8 alo = *(const bf16x8*)(wa_l + (size_t)(S0 + J) * 2048); \
    c0 = MFMA_BF16(ahi, BH, c0, 0, 0, 0); \
    c1 = MFMA_BF16(ahi, BL, c1, 0, 0, 0); \
    c2 = MFMA_BF16(alo, BH, c2, 0, 0, 0); }
    KSTEP(0, b.h0, b.l0) KSTEP(1, b.h1, b.l1) KSTEP(2, b.h2, b.l2) KSTEP(3, b.h3, b.l3)
    KSTEP(4, b.h4, b.l4) KSTEP(5, b.h5, b.l5) KSTEP(6, b.h6, b.l6) KSTEP(7, b.h7, b.l7)
#undef KSTEP
}

// 32-kstep panel, 3 batches in flight.
template<int S0>
__device__ __forceinline__ void panel32(const char* rb,
                                        const char* wa_h, const char* wa_l,
                                        f32x16& c0, f32x16& c1, f32x16& c2) {
    B8 A, B, C;
    issue8(rb, A);
    issue8(rb + 32768, B);
    issue8(rb + 65536, C);
    wait32(A); consume8<S0>(wa_h, wa_l, A, c0, c1, c2);
    issue8(rb + 98304, A);
    wait32(B); consume8<S0 + 8>(wa_h, wa_l, B, c0, c1, c2);
    wait16(C); consume8<S0 + 16>(wa_h, wa_l, C, c0, c1, c2);
    wait0(A);  consume8<S0 + 24>(wa_h, wa_l, A, c0, c1, c2);
}
template<int S0>
__device__ __forceinline__ void panel16(const char* rb,
                                        const char* wa_h, const char* wa_l,
                                        f32x16& c0, f32x16& c1, f32x16& c2) {
    B8 A, B;
    issue8(rb, A);
    issue8(rb + 32768, B);
    wait16(A); consume8<S0>(wa_h, wa_l, A, c0, c1, c2);
    wait0(B);  consume8<S0 + 8>(wa_h, wa_l, B, c0, c1, c2);
}

// x [B,T,I] -> xTq [t][grp][b][hi 16B | lo 16B]
__global__ __launch_bounds__(256) void pack_x(const float* __restrict__ x,
                                              char* __restrict__ xTq) {
    const int t = blockIdx.x;
    const int b = threadIdx.x & 63;
    const int gq = threadIdx.x >> 6;
    #pragma unroll
    for (int gi = 0; gi < 2; ++gi) {
        const int g2 = gq + gi * 4;
        const float* src = x + ((size_t)b * TT + t) * II + g2 * 8;
        float w[8];
        *(float4*)&w[0] = *(const float4*)src;
        *(float4*)&w[4] = *(const float4*)(src + 4);
        bf16x8 hv, lv;
        #pragma unroll
        for (int j = 0; j < 8; ++j) {
            unsigned short h = f2bf(w[j]);
            hv[j] = (short)h;
            lv[j] = (short)f2bf(w[j] - bf2f(h));
        }
        char* dst = xTq + (((size_t)t * 8 + g2) * 64 + b) * 32;
        *(bf16x8*)dst = hv;
        *(bf16x8*)(dst + 16) = lv;
    }
}

// Pack 32 gate-rows into LDS in MFMA A-fragment order (swizzled layout).
template<int IN_DIM, int NKS>
__device__ void pack_weights(const float* __restrict__ Wih, const float* __restrict__ Whh,
                             int hbase, char* __restrict__ WAc) {
    const int lane = threadIdx.x & 63;
    const int wq = threadIdx.x >> 6;
    const int m = lane & 31;
    const int lg = lane >> 5;
    const int swz = (lane & 28) << 2;
    const int off_h = (lane * 32) ^ swz;
    const int off_l = (lane * 32 + 16) ^ swz;
    const int grow = (m >> 3) * HH + hbase + (m & 7);
    const float* wi = Wih + (size_t)grow * IN_DIM;
    const float* wh = Whh + (size_t)grow * HH;
    for (int s = wq; s < NKS; s += 4) {
        const int k8 = s * 16 + lg * 8;
        const float* src = (k8 < IN_DIM) ? (wi + k8) : (wh + (k8 - IN_DIM));
        float w[8];
        *(float4*)&w[0] = *(const float4*)src;
        *(float4*)&w[4] = *(const float4*)(src + 4);
        bf16x8 hv, lv;
        #pragma unroll
        for (int j = 0; j < 8; ++j) {
            unsigned short h = f2bf(w[j]);
            hv[j] = (short)h;
            lv[j] = (short)f2bf(w[j] - bf2f(h));
        }
        char* dst = WAc + (size_t)s * 2048;
        *(bf16x8*)(dst + off_h) = hv;
        *(bf16x8*)(dst + off_l) = lv;
    }
}

// hbuf_l: [parity][grp=64][b=64][hi16|lo16] — written by layer l (write-through),
// read by layer l (h-part, parity t&1) and layer l+1 (x-part, parity (t+1)&1)
// via CACHED loads after a per-step l2_inv().
template<int LAYER, int IN_DIM, int NKS, int KH>
__device__ void lstm_core(int tile,
                          const char* __restrict__ xTq,
                          const char* __restrict__ hbuf_prev, char* __restrict__ hbuf,
                          float* __restrict__ h2last, unsigned* __restrict__ flags,
                          const float* __restrict__ Wih, const float* __restrict__ Whh,
                          const float* __restrict__ bih, const float* __restrict__ bhh,
                          char* __restrict__ WAc, float* __restrict__ redbuf) {
    const int tid = threadIdx.x;
    const int lane = tid & 63;
    const int wq = tid >> 6;
    const int ntile = wq & 1;
    const int khalf = wq >> 1;
    const int lg = lane >> 5;
    const int b = ntile * 32 + (lane & 31);
    const int hbase = tile * 8;

    pack_weights<IN_DIM, NKS>(Wih, Whh, hbase, WAc);

    float bias_v[16];
    float cst[4] = {0.f, 0.f, 0.f, 0.f};
    if (khalf == 0) {
        #pragma unroll
        for (int g = 0; g < 4; ++g)
            #pragma unroll
            for (int j = 0; j < 4; ++j) {
                const int grow = g * HH + hbase + j + 4 * lg;
                bias_v[g * 4 + j] = bih[grow] + bhh[grow];
            }
    }
    __syncthreads();   // WA ready

    const int swz = (lane & 28) << 2;
    const char* wa_h = WAc + ((lane * 32) ^ swz);
    const char* wa_l = WAc + ((lane * 32 + 16) ^ swz);

    unsigned* const arr_own  = flags + (size_t)(LAYER * 64) * FLAG_STRIDE;
    const unsigned* arr_prev = (LAYER > 0) ? flags + (size_t)((LAYER - 1) * 64) * FLAG_STRIDE : arr_own;
    const unsigned* arr_next = (LAYER < 2) ? flags + (size_t)((LAYER + 1) * 64) * FLAG_STRIDE : arr_own;
    unsigned* const my_flag  = arr_own + (size_t)tile * FLAG_STRIDE;
    const int xoff = lg * 2048 + b * 32;

    for (int t = 0; t < TT; ++t) {
        f32x16 c0 = {0,0,0,0,0,0,0,0,0,0,0,0,0,0,0,0};
        f32x16 c1 = c0, c2 = c0;
        const char* rb_h = hbuf + (size_t)(t & 1) * 131072 + xoff;            // h(t-1)
        const char* rb_x = hbuf_prev + (size_t)((t + 1) & 1) * 131072 + xoff; // x(t)=h_{l-1}(t)

        if (khalf == 0) {
            if (LAYER == 0) {
                const char* xq = xTq + (size_t)t * 16384 + xoff;
                #pragma unroll
                for (int s = 0; s < 4; ++s) {
                    bf16x8 bh = *(const bf16x8*)(xq + (size_t)s * 4096);
                    bf16x8 bl = *(const bf16x8*)(xq + (size_t)s * 4096 + 16);
                    bf16x8 ahi = *(const bf16x8*)(wa_h + (size_t)s * 2048);
                    bf16x8 alo = *(const bf16x8*)(wa_l + (size_t)s * 2048);
                    c0 = MFMA_BF16(ahi, bh, c0, 0, 0, 0);
                    c1 = MFMA_BF16(ahi, bl, c1, 0, 0, 0);
                    c2 = MFMA_BF16(alo, bh, c2, 0, 0, 0);
                }
                if (t > 0) {
                    poll_ge64(arr_own, (unsigned)t);                  // h(t-1) ready
                    l2_inv();                                         // fresh L1/L2 view
                    panel16<4>(rb_h, wa_h, wa_l, c0, c1, c2);
                }
            } else {
                poll_ge64(arr_prev, (unsigned)(t + 1));               // x(t) ready
                l2_inv();
                panel32<0>(rb_x, wa_h, wa_l, c0, c1, c2);
            }
        } else {
            if (t > 0) {
                poll_ge64(arr_own, (unsigned)t);                      // h(t-1) ready
                l2_inv();
                if (LAYER == 0) panel16<20>(rb_h + 65536, wa_h, wa_l, c0, c1, c2);
                else            panel32<32>(rb_h, wa_h, wa_l, c0, c1, c2);
            }
        }

        f32x16 cs = c0 + c1 + c2;

        if (khalf == 1) {
            float* pw = &redbuf[((size_t)ntile * 64 + lane) * 20];
            #pragma unroll
            for (int q = 0; q < 4; ++q) {
                float4 v; v.x = cs[q*4+0]; v.y = cs[q*4+1]; v.z = cs[q*4+2]; v.w = cs[q*4+3];
                *(float4*)(pw + q * 4) = v;
            }
        }
        __syncthreads();
        if (khalf == 0) {
            const float* pr = &redbuf[((size_t)ntile * 64 + lane) * 20];
            float prv[16];
            #pragma unroll
            for (int q = 0; q < 4; ++q)
                *(float4*)&prv[q * 4] = *(const float4*)(pr + q * 4);
            float gate[16];
            #pragma unroll
            for (int r = 0; r < 16; ++r) gate[r] = cs[r] + prv[r] + bias_v[r];

            unsigned short his[4], los[4];
            #pragma unroll
            for (int j = 0; j < 4; ++j) {
                const float iv = sigmoidf_(gate[0 + j]);
                const float fv = sigmoidf_(gate[4 + j]);
                const float gv = tanhf(gate[8 + j]);
                const float ov = sigmoidf_(gate[12 + j]);
                cst[j] = fv * cst[j] + iv * gv;
                const float hv = ov * tanhf(cst[j]);
                his[j] = f2bf(hv);
                los[j] = f2bf(hv - bf2f(his[j]));
                if (LAYER == 2 && t == TT - 1)
                    storef_thru(h2last + (size_t)(hbase + j + 4 * lg) * 64 + b, hv);
            }
            unsigned long long hi2 = (unsigned long long)((unsigned)his[0] | ((unsigned)his[1] << 16))
                                   | ((unsigned long long)((unsigned)his[2] | ((unsigned)his[3] << 16)) << 32);
            unsigned long long lo2 = (unsigned long long)((unsigned)los[0] | ((unsigned)los[1] << 16))
                                   | ((unsigned long long)((unsigned)los[2] | ((unsigned)los[3] << 16)) << 32);

            // h(t) -> parity (t+1)&1 overwrites h(t-2); next-layer readers of
            // h(t-2) must be done: next flags >= t-1.
            if (LAYER < 2 && t >= 2) poll_ge64(arr_next, (unsigned)(t - 1));
            char* d2 = hbuf + (size_t)((t + 1) & 1) * 131072 + (size_t)tile * 2048 + b * 32 + lg * 8;
            store8_thru(d2, hi2);
            store8_thru(d2 + 16, lo2);
        }
        // publish: every wave drains its stores, then one flag store
        __builtin_amdgcn_s_waitcnt(0);
        __syncthreads();
        if (tid == 0) storeu_thru(my_flag, (unsigned)(t + 1));
    }
}

__global__ __launch_bounds__(256, 1) void lstm_wavefront(
    const char* __restrict__ xTq,
    char* __restrict__ hbuf0, char* __restrict__ hbuf1, char* __restrict__ hbuf2,
    float* __restrict__ h2last, unsigned* __restrict__ flags,
    const float* __restrict__ Wih0, const float* __restrict__ Whh0,
    const float* __restrict__ bih0, const float* __restrict__ bhh0,
    const float* __restrict__ Wih1, const float* __restrict__ Whh1,
    const float* __restrict__ bih1, const float* __restrict__ bhh1,
    const float* __restrict__ Wih2, const float* __restrict__ Whh2,
    const float* __restrict__ bih2, const float* __restrict__ bhh2,
    const float* __restrict__ fcw, const float* __restrict__ fcb,
    float* __restrict__ out) {

    __shared__ short WA[64 * 64 * 16];     // 128 KB
    __shared__ float redbuf[2 * 64 * 20];  // 10 KB
    __shared__ float fcred[256];

    // XCD-grouped remap: physical p -> logical g so each XCD (p%8) hosts 24
    // consecutive logical blocks => (mostly) one layer per XCD => invs cluster
    // and same-layer panel reads share L2.
    const int p = blockIdx.x;
    const int g = (p & 7) * 24 + (p >> 3);
    const int l = g >> 6;
    const int tile = g & 63;
    char* WAc = (char*)WA;

    if (l == 0)
        lstm_core<0, II, 36, 20>(tile, xTq, nullptr, hbuf0, h2last, flags,
                                 Wih0, Whh0, bih0, bhh0, WAc, redbuf);
    else if (l == 1)
        lstm_core<1, HH, 64, 32>(tile, xTq, hbuf0, hbuf1, h2last, flags,
                                 Wih1, Whh1, bih1, bhh1, WAc, redbuf);
    else
        lstm_core<2, HH, 64, 32>(tile, xTq, hbuf1, hbuf2, h2last, flags,
                                 Wih2, Whh2, bih2, bhh2, WAc, redbuf);

    // final FC on h2[T-1]
    if (p == 0) {
        if (threadIdx.x < 64)
            poll_ge64(flags + (size_t)(2 * 64) * FLAG_STRIDE, (unsigned)TT);
        __syncthreads();
        const int tid = threadIdx.x;
        const int b = tid & 63, kq = tid >> 6;
        float s = 0.f;
        const float* hp = h2last + (size_t)kq * 128 * 64 + b;
        const float* wp = fcw + kq * 128;
        #pragma unroll 8
        for (int k = 0; k < 128; ++k)
            s = fmaf(loadf_byp(hp + (size_t)k * 64), wp[k], s);
        fcred[tid] = s;
        __syncthreads();
        if (tid < 64)
            out[tid] = fcred[tid] + fcred[64 + tid] + fcred[128 + tid] + fcred[192 + tid] + fcb[0];
    }
}

extern "C" void kernel_launch(void* const* d_in, const int* in_sizes, int n_in,
                              void* d_out, int out_size, void* d_ws, size_t ws_size,
                              hipStream_t stream) {
    (void)in_sizes; (void)n_in; (void)out_size; (void)ws_size;

    const float* x    = (const float*)d_in[0];
    const float* Wih0 = (const float*)d_in[1];
    const float* Whh0 = (const float*)d_in[2];
    const float* bih0 = (const float*)d_in[3];
    const float* bhh0 = (const float*)d_in[4];
    const float* Wih1 = (const float*)d_in[5];
    const float* Whh1 = (const float*)d_in[6];
    const float* bih1 = (const float*)d_in[7];
    const float* bhh1 = (const float*)d_in[8];
    const float* Wih2 = (const float*)d_in[9];
    const float* Whh2 = (const float*)d_in[10];
    const float* bih2 = (const float*)d_in[11];
    const float* bhh2 = (const float*)d_in[12];
    const float* fcw  = (const float*)d_in[13];
    const float* fcb  = (const float*)d_in[14];

    char* ws = (char*)d_ws;
    unsigned* flags = (unsigned*)ws;                       // 24 KB
    char* hbuf0   = ws + 65536;                            // 2*64*64*32 = 256 KB each
    char* hbuf1   = hbuf0 + 2 * 64 * 64 * 32;
    char* hbuf2   = hbuf1 + 2 * 64 * 64 * 32;
    float* h2last = (float*)(hbuf2 + 2 * 64 * 64 * 32);    // 128 KB
    char* xTq     = (char*)h2last + 512 * 64 * 4;          // 8 MB

    hipMemsetAsync(ws, 0, 65536, stream);

    pack_x<<<TT, 256, 0, stream>>>(x, xTq);

    lstm_wavefront<<<NBLK, 256, 0, stream>>>(
        xTq, hbuf0, hbuf1, hbuf2, h2last, flags,
        Wih0, Whh0, bih0, bhh0,
        Wih1, Whh1, bih1, bhh1,
        Wih2, Whh2, bih2, bhh2,
        fcw, fcb, (float*)d_out);
}

// Round 13
// 2614.567 us; speedup vs baseline: 2.2960x; 2.2960x over previous
//
#include <hip/hip_runtime.h>
#include <math.h>

#define BB 64
#define TT 512
#define II 64
#define HH 512
#define NBLK 192
#define FLAG_STRIDE 32   // dwords = 128 B between flags

typedef __attribute__((ext_vector_type(8))) _Float16 f16x8;
typedef __attribute__((ext_vector_type(16))) float f32x16;

__device__ __forceinline__ float sigmoidf_(float x) {
    return 1.0f / (1.0f + expf(-x));
}

// --- coherent scalar primitives (compiler-tracked) ---
__device__ __forceinline__ void store8_thru(void* p, unsigned long long u) {
    __hip_atomic_store((unsigned long long*)p, u, __ATOMIC_RELAXED, __HIP_MEMORY_SCOPE_AGENT);
}
__device__ __forceinline__ void storef_thru(float* p, float v) {
    __hip_atomic_store(p, v, __ATOMIC_RELAXED, __HIP_MEMORY_SCOPE_AGENT);
}
__device__ __forceinline__ float loadf_byp(const float* p) {
    return __hip_atomic_load(p, __ATOMIC_RELAXED, __HIP_MEMORY_SCOPE_AGENT);
}
__device__ __forceinline__ void storeu_thru(unsigned* p, unsigned v) {
    __hip_atomic_store(p, v, __ATOMIC_RELAXED, __HIP_MEMORY_SCOPE_AGENT);
}
__device__ __forceinline__ unsigned loadu_byp(const unsigned* p) {
    return __hip_atomic_load(p, __ATOMIC_RELAXED, __HIP_MEMORY_SCOPE_AGENT);
}

// Wave-parallel direct poll: lane i watches producer i's spread flag line.
__device__ __forceinline__ void poll_ge64(const unsigned* flags, unsigned tgt) {
    const int lane = threadIdx.x & 63;
    const unsigned* a = flags + (size_t)lane * FLAG_STRIDE;
    unsigned f = loadu_byp(a);
    while (__ballot(f < tgt) != 0ull) {
        __builtin_amdgcn_s_sleep(1);
        f = loadu_byp(a);
    }
}

// --- 16B-bypass batched loads: 8 ksteps = 8 dwordx4, stride 2048B ---
struct B8 { f16x8 v0, v1, v2, v3, v4, v5, v6, v7; };

__device__ __forceinline__ void issue8(const char* rb, B8& b) {
    const char* p0 = rb;
    const char* p1 = rb + 2048;
    const char* p2 = rb + 4096;
    const char* p3 = rb + 6144;
    const char* p4 = rb + 8192;
    const char* p5 = rb + 10240;
    const char* p6 = rb + 12288;
    const char* p7 = rb + 14336;
    asm volatile(
        "global_load_dwordx4 %0, %8, off sc0 sc1\n\t"
        "global_load_dwordx4 %1, %9, off sc0 sc1\n\t"
        "global_load_dwordx4 %2, %10, off sc0 sc1\n\t"
        "global_load_dwordx4 %3, %11, off sc0 sc1\n\t"
        "global_load_dwordx4 %4, %12, off sc0 sc1\n\t"
        "global_load_dwordx4 %5, %13, off sc0 sc1\n\t"
        "global_load_dwordx4 %6, %14, off sc0 sc1\n\t"
        "global_load_dwordx4 %7, %15, off sc0 sc1"
        : "=&v"(b.v0), "=&v"(b.v1), "=&v"(b.v2), "=&v"(b.v3),
          "=&v"(b.v4), "=&v"(b.v5), "=&v"(b.v6), "=&v"(b.v7)
        : "v"(p0), "v"(p1), "v"(p2), "v"(p3), "v"(p4), "v"(p5), "v"(p6), "v"(p7));
}

// Counted waits; staged values tied through the asm (+sched_barrier, rule #18).
#define DEF_WAIT(NAME, CNT) \
__device__ __forceinline__ void NAME(B8& b) { \
    asm volatile("s_waitcnt vmcnt(" #CNT ")" \
        : "+v"(b.v0), "+v"(b.v1), "+v"(b.v2), "+v"(b.v3), \
          "+v"(b.v4), "+v"(b.v5), "+v"(b.v6), "+v"(b.v7)); \
    __builtin_amdgcn_sched_barrier(0); \
}
DEF_WAIT(wait16, 16)
DEF_WAIT(wait8, 8)
DEF_WAIT(wait0, 0)

#define MFMA_F16 __builtin_amdgcn_mfma_f32_32x32x16_f16

template<int S0>
__device__ __forceinline__ void consume8(const char* wa_h, const char* wa_l, const B8& b,
                                         f32x16& c0, f32x16& c2) {
#define KSTEP(J, BV) { \
    f16x8 ahi = *(const f16x8*)(wa_h + (size_t)(S0 + J) * 2048); \
    f16x8 alo = *(const f16x8*)(wa_l + (size_t)(S0 + J) * 2048); \
    c0 = MFMA_F16(ahi, BV, c0, 0, 0, 0); \
    c2 = MFMA_F16(alo, BV, c2, 0, 0, 0); }
    KSTEP(0, b.v0) KSTEP(1, b.v1) KSTEP(2, b.v2) KSTEP(3, b.v3)
    KSTEP(4, b.v4) KSTEP(5, b.v5) KSTEP(6, b.v6) KSTEP(7, b.v7)
#undef KSTEP
}

// 32-kstep panel, 3 batches (24 loads) in flight.
template<int S0>
__device__ __forceinline__ void panel32(const char* rb,
                                        const char* wa_h, const char* wa_l,
                                        f32x16& c0, f32x16& c2) {
    B8 A, B, C;
    issue8(rb, A);
    issue8(rb + 16384, B);
    issue8(rb + 32768, C);
    wait16(A); consume8<S0>(wa_h, wa_l, A, c0, c2);
    issue8(rb + 49152, A);                                  // batch D reuses A's regs
    wait16(B); consume8<S0 + 8>(wa_h, wa_l, B, c0, c2);
    wait8(C);  consume8<S0 + 16>(wa_h, wa_l, C, c0, c2);
    wait0(A);  consume8<S0 + 24>(wa_h, wa_l, A, c0, c2);
}
template<int S0>
__device__ __forceinline__ void panel16(const char* rb,
                                        const char* wa_h, const char* wa_l,
                                        f32x16& c0, f32x16& c2) {
    B8 A, B;
    issue8(rb, A);
    issue8(rb + 16384, B);
    wait8(A); consume8<S0>(wa_h, wa_l, A, c0, c2);
    wait0(B); consume8<S0 + 8>(wa_h, wa_l, B, c0, c2);
}

// x [B,T,I] -> xTq [t][grp=8][b=64][16B f16], grp = i>>3
__global__ __launch_bounds__(256) void pack_x(const float* __restrict__ x,
                                              char* __restrict__ xTq) {
    const int t = blockIdx.x;
    const int b = threadIdx.x & 63;
    const int gq = threadIdx.x >> 6;
    #pragma unroll
    for (int gi = 0; gi < 2; ++gi) {
        const int g2 = gq + gi * 4;
        const float* src = x + ((size_t)b * TT + t) * II + g2 * 8;
        float w[8];
        *(float4*)&w[0] = *(const float4*)src;
        *(float4*)&w[4] = *(const float4*)(src + 4);
        f16x8 hv;
        #pragma unroll
        for (int j = 0; j < 8; ++j) hv[j] = (_Float16)w[j];
        *(f16x8*)(xTq + (((size_t)t * 8 + g2) * 64 + b) * 16) = hv;
    }
}

// Pack 32 gate-rows into LDS in MFMA A-fragment order (swizzled), f16 hi+lo
// split: w = whi + wlo captures fp32 weights to ~2^-24.
template<int IN_DIM, int NKS>
__device__ void pack_weights(const float* __restrict__ Wih, const float* __restrict__ Whh,
                             int hbase, char* __restrict__ WAc) {
    const int lane = threadIdx.x & 63;
    const int wq = threadIdx.x >> 6;
    const int m = lane & 31;
    const int lg = lane >> 5;
    const int swz = (lane & 28) << 2;
    const int off_h = (lane * 32) ^ swz;
    const int off_l = (lane * 32 + 16) ^ swz;
    const int grow = (m >> 3) * HH + hbase + (m & 7);
    const float* wi = Wih + (size_t)grow * IN_DIM;
    const float* wh = Whh + (size_t)grow * HH;
    for (int s = wq; s < NKS; s += 4) {
        const int k8 = s * 16 + lg * 8;
        const float* src = (k8 < IN_DIM) ? (wi + k8) : (wh + (k8 - IN_DIM));
        float w[8];
        *(float4*)&w[0] = *(const float4*)src;
        *(float4*)&w[4] = *(const float4*)(src + 4);
        f16x8 hv, lv;
        #pragma unroll
        for (int j = 0; j < 8; ++j) {
            _Float16 h = (_Float16)w[j];
            hv[j] = h;
            lv[j] = (_Float16)(w[j] - (float)h);
        }
        char* dst = WAc + (size_t)s * 2048;
        *(f16x8*)(dst + off_h) = hv;
        *(f16x8*)(dst + off_l) = lv;
    }
}

// hbuf_l: [parity][grp=64][b=64][16B f16] (64KB/parity) — written by layer l,
// read by layer l (h-part, parity t&1) and layer l+1 (x-part, parity (t+1)&1).
template<int LAYER, int IN_DIM, int NKS, int KH>
__device__ void lstm_core(int tile,
                          const char* __restrict__ xTq,
                          const char* __restrict__ hbuf_prev, char* __restrict__ hbuf,
                          float* __restrict__ h2last, unsigned* __restrict__ flags,
                          const float* __restrict__ Wih, const float* __restrict__ Whh,
                          const float* __restrict__ bih, const float* __restrict__ bhh,
                          char* __restrict__ WAc, float* __restrict__ redbuf) {
    const int tid = threadIdx.x;
    const int lane = tid & 63;
    const int wq = tid >> 6;
    const int ntile = wq & 1;
    const int khalf = wq >> 1;
    const int lg = lane >> 5;
    const int b = ntile * 32 + (lane & 31);
    const int hbase = tile * 8;

    pack_weights<IN_DIM, NKS>(Wih, Whh, hbase, WAc);

    float bias_v[16];
    float cst[4] = {0.f, 0.f, 0.f, 0.f};
    if (khalf == 0) {
        #pragma unroll
        for (int g = 0; g < 4; ++g)
            #pragma unroll
            for (int j = 0; j < 4; ++j) {
                const int grow = g * HH + hbase + j + 4 * lg;
                bias_v[g * 4 + j] = bih[grow] + bhh[grow];
            }
    }
    __syncthreads();   // WA ready

    const int swz = (lane & 28) << 2;
    const char* wa_h = WAc + ((lane * 32) ^ swz);
    const char* wa_l = WAc + ((lane * 32 + 16) ^ swz);

    unsigned* const arr_own  = flags + (size_t)(LAYER * 64) * FLAG_STRIDE;
    const unsigned* arr_prev = (LAYER > 0) ? flags + (size_t)((LAYER - 1) * 64) * FLAG_STRIDE : arr_own;
    const unsigned* arr_next = (LAYER < 2) ? flags + (size_t)((LAYER + 1) * 64) * FLAG_STRIDE : arr_own;
    unsigned* const my_flag  = arr_own + (size_t)tile * FLAG_STRIDE;
    const int xoff = lg * 1024 + b * 16;

    for (int t = 0; t < TT; ++t) {
        f32x16 c0 = {0,0,0,0,0,0,0,0,0,0,0,0,0,0,0,0};
        f32x16 c2 = c0;
        const char* rb_h = hbuf + (size_t)(t & 1) * 65536 + xoff;            // h(t-1)
        const char* rb_x = hbuf_prev + (size_t)((t + 1) & 1) * 65536 + xoff; // x(t)=h_{l-1}(t)

        // Each wave polls only ITS dependency; the redbuf __syncthreads joins.
        if (khalf == 0) {
            if (LAYER == 0) {
                // x-part: 4 plain cached ksteps from xTq — no gate needed
                const char* xq = xTq + (size_t)t * 8192 + xoff;
                #pragma unroll
                for (int s = 0; s < 4; ++s) {
                    f16x8 bv = *(const f16x8*)(xq + (size_t)s * 2048);
                    f16x8 ahi = *(const f16x8*)(wa_h + (size_t)s * 2048);
                    f16x8 alo = *(const f16x8*)(wa_l + (size_t)s * 2048);
                    c0 = MFMA_F16(ahi, bv, c0, 0, 0, 0);
                    c2 = MFMA_F16(alo, bv, c2, 0, 0, 0);
                }
                if (t > 0) {
                    poll_ge64(arr_own, (unsigned)t);                  // h(t-1) ready
                    panel16<4>(rb_h, wa_h, wa_l, c0, c2);             // ring ksteps 4..19
                }
            } else {
                poll_ge64(arr_prev, (unsigned)(t + 1));               // x(t) ready
                panel32<0>(rb_x, wa_h, wa_l, c0, c2);                 // x ksteps 0..31
            }
        } else {
            if (t > 0) {
                poll_ge64(arr_own, (unsigned)t);                      // h(t-1) ready
                if (LAYER == 0) panel16<20>(rb_h + 32768, wa_h, wa_l, c0, c2);
                else            panel32<32>(rb_h, wa_h, wa_l, c0, c2);
            }
        }

        f32x16 cs = c0 + c2;

        if (khalf == 1) {
            float* pw = &redbuf[((size_t)ntile * 64 + lane) * 20];
            #pragma unroll
            for (int q = 0; q < 4; ++q) {
                float4 v; v.x = cs[q*4+0]; v.y = cs[q*4+1]; v.z = cs[q*4+2]; v.w = cs[q*4+3];
                *(float4*)(pw + q * 4) = v;
            }
        }
        __syncthreads();
        if (khalf == 0) {
            const float* pr = &redbuf[((size_t)ntile * 64 + lane) * 20];
            float prv[16];
            #pragma unroll
            for (int q = 0; q < 4; ++q)
                *(float4*)&prv[q * 4] = *(const float4*)(pr + q * 4);
            float gate[16];
            #pragma unroll
            for (int r = 0; r < 16; ++r) gate[r] = cs[r] + prv[r] + bias_v[r];

            union { _Float16 h[4]; unsigned long long u; } hp;
            #pragma unroll
            for (int j = 0; j < 4; ++j) {
                const float iv = sigmoidf_(gate[0 + j]);
                const float fv = sigmoidf_(gate[4 + j]);
                const float gv = tanhf(gate[8 + j]);
                const float ov = sigmoidf_(gate[12 + j]);
                cst[j] = fv * cst[j] + iv * gv;
                const float hv = ov * tanhf(cst[j]);
                hp.h[j] = (_Float16)hv;
                if (LAYER == 2 && t == TT - 1)
                    storef_thru(h2last + (size_t)(hbase + j + 4 * lg) * 64 + b, hv);
            }

            // h(t) -> parity (t+1)&1 overwrites h(t-2); next-layer readers of
            // h(t-2) must be done: next flags >= t-1.
            if (LAYER < 2 && t >= 2) poll_ge64(arr_next, (unsigned)(t - 1));
            // grp = tile; k-in-grp = j + 4*lg -> 4 contiguous f16 at byte lg*8
            char* d2 = hbuf + (size_t)((t + 1) & 1) * 65536 + (size_t)tile * 1024 + b * 16 + lg * 8;
            store8_thru(d2, hp.u);
        }
        // publish: every wave drains its stores, then one flag store
        __builtin_amdgcn_s_waitcnt(0);
        __syncthreads();
        if (tid == 0) storeu_thru(my_flag, (unsigned)(t + 1));
    }
}

__global__ __launch_bounds__(256, 1) void lstm_wavefront(
    const char* __restrict__ xTq,
    char* __restrict__ hbuf0, char* __restrict__ hbuf1, char* __restrict__ hbuf2,
    float* __restrict__ h2last, unsigned* __restrict__ flags,
    const float* __restrict__ Wih0, const float* __restrict__ Whh0,
    const float* __restrict__ bih0, const float* __restrict__ bhh0,
    const float* __restrict__ Wih1, const float* __restrict__ Whh1,
    const float* __restrict__ bih1, const float* __restrict__ bhh1,
    const float* __restrict__ Wih2, const float* __restrict__ Whh2,
    const float* __restrict__ bih2, const float* __restrict__ bhh2,
    const float* __restrict__ fcw, const float* __restrict__ fcb,
    float* __restrict__ out) {

    __shared__ short WA[64 * 64 * 16];     // 128 KB (f16 hi/lo A-fragments)
    __shared__ float redbuf[2 * 64 * 20];  // 10 KB
    __shared__ float fcred[256];

    const int l = blockIdx.x >> 6;
    const int tile = blockIdx.x & 63;
    char* WAc = (char*)WA;

    if (l == 0)
        lstm_core<0, II, 36, 20>(tile, xTq, nullptr, hbuf0, h2last, flags,
                                 Wih0, Whh0, bih0, bhh0, WAc, redbuf);
    else if (l == 1)
        lstm_core<1, HH, 64, 32>(tile, xTq, hbuf0, hbuf1, h2last, flags,
                                 Wih1, Whh1, bih1, bhh1, WAc, redbuf);
    else
        lstm_core<2, HH, 64, 32>(tile, xTq, hbuf1, hbuf2, h2last, flags,
                                 Wih2, Whh2, bih2, bhh2, WAc, redbuf);

    // final FC on h2[T-1]
    if (blockIdx.x == 0) {
        if (threadIdx.x < 64)
            poll_ge64(flags + (size_t)(2 * 64) * FLAG_STRIDE, (unsigned)TT);
        __syncthreads();
        const int tid = threadIdx.x;
        const int b = tid & 63, kq = tid >> 6;
        float s = 0.f;
        const float* hp = h2last + (size_t)kq * 128 * 64 + b;
        const float* wp = fcw + kq * 128;
        #pragma unroll 8
        for (int k = 0; k < 128; ++k)
            s = fmaf(loadf_byp(hp + (size_t)k * 64), wp[k], s);
        fcred[tid] = s;
        __syncthreads();
        if (tid < 64)
            out[tid] = fcred[tid] + fcred[64 + tid] + fcred[128 + tid] + fcred[192 + tid] + fcb[0];
    }
}

extern "C" void kernel_launch(void* const* d_in, const int* in_sizes, int n_in,
                              void* d_out, int out_size, void* d_ws, size_t ws_size,
                              hipStream_t stream) {
    (void)in_sizes; (void)n_in; (void)out_size; (void)ws_size;

    const float* x    = (const float*)d_in[0];
    const float* Wih0 = (const float*)d_in[1];
    const float* Whh0 = (const float*)d_in[2];
    const float* bih0 = (const float*)d_in[3];
    const float* bhh0 = (const float*)d_in[4];
    const float* Wih1 = (const float*)d_in[5];
    const float* Whh1 = (const float*)d_in[6];
    const float* bih1 = (const float*)d_in[7];
    const float* bhh1 = (const float*)d_in[8];
    const float* Wih2 = (const float*)d_in[9];
    const float* Whh2 = (const float*)d_in[10];
    const float* bih2 = (const float*)d_in[11];
    const float* bhh2 = (const float*)d_in[12];
    const float* fcw  = (const float*)d_in[13];
    const float* fcb  = (const float*)d_in[14];

    char* ws = (char*)d_ws;
    unsigned* flags = (unsigned*)ws;                       // 24 KB (spread flags)
    char* hbuf0   = ws + 65536;                            // 2*64KB = 128 KB each
    char* hbuf1   = hbuf0 + 2 * 64 * 64 * 16;
    char* hbuf2   = hbuf1 + 2 * 64 * 64 * 16;
    float* h2last = (float*)(hbuf2 + 2 * 64 * 64 * 16);    // 128 KB
    char* xTq     = (char*)h2last + 512 * 64 * 4;          // 4 MB

    hipMemsetAsync(ws, 0, 65536, stream);

    pack_x<<<TT, 256, 0, stream>>>(x, xTq);

    lstm_wavefront<<<NBLK, 256, 0, stream>>>(
        xTq, hbuf0, hbuf1, hbuf2, h2last, flags,
        Wih0, Whh0, bih0, bhh0,
        Wih1, Whh1, bih1, bhh1,
        Wih2, Whh2, bih2, bhh2,
        fcw, fcb, (float*)d_out);
}